// Round 1
// baseline (207.811 us; speedup 1.0000x reference)
//
#include <hip/hip_runtime.h>

#define SEQ 8
#define DIM 16
#define FF 32
#define VOCAB 256
#define ITEMS_PER_BLOCK 32
#define ITEM_STRIDE 136  // 8 rows * 16 dwords + 8 pad dwords (breaks bank aliasing)

__global__ __launch_bounds__(256) void transformer_fused_kernel(
    const int* __restrict__ x,
    const float* __restrict__ token_embed,
    const float* __restrict__ pos_embed,
    const float* __restrict__ Wq, const float* __restrict__ bq,
    const float* __restrict__ Wk, const float* __restrict__ bk,
    const float* __restrict__ Wv, const float* __restrict__ bv,
    const float* __restrict__ Wo, const float* __restrict__ bo,
    const float* __restrict__ W1, const float* __restrict__ b1,
    const float* __restrict__ W2, const float* __restrict__ b2,
    const float* __restrict__ Wh, const float* __restrict__ bh,
    float* __restrict__ out)
{
    __shared__ float sK[ITEMS_PER_BLOCK * ITEM_STRIDE];
    __shared__ float sV[ITEMS_PER_BLOCK * ITEM_STRIDE];

    const int tid = threadIdx.x;
    const int i = tid >> 3;   // local batch item 0..31
    const int n = tid & 7;    // seq position 0..7
    const int b = blockIdx.x * ITEMS_PER_BLOCK + i;

    // ---------------- phase 1: embedding + QKV ----------------
    float X[DIM];
    {
        const int idx = x[b * SEQ + n];
        const float4* te = (const float4*)(token_embed + idx * DIM);
        const float4* pe = (const float4*)(pos_embed + n * DIM);
        #pragma unroll
        for (int j = 0; j < 4; ++j) {
            float4 a = te[j];
            float4 p = pe[j];
            X[4*j+0] = a.x + p.x;
            X[4*j+1] = a.y + p.y;
            X[4*j+2] = a.z + p.z;
            X[4*j+3] = a.w + p.w;
        }
    }

    float Q[DIM], Kr[DIM], Vr[DIM];
    #pragma unroll
    for (int e = 0; e < DIM; ++e) {
        float q = bq[e], k = bk[e], v = bv[e];
        #pragma unroll
        for (int d = 0; d < DIM; ++d) {
            q += X[d] * Wq[d * DIM + e];
            k += X[d] * Wk[d * DIM + e];
            v += X[d] * Wv[d * DIM + e];
        }
        Q[e] = q; Kr[e] = k; Vr[e] = v;
    }

    // park K,V rows in LDS
    {
        float* kdst = sK + i * ITEM_STRIDE + n * DIM;
        float* vdst = sV + i * ITEM_STRIDE + n * DIM;
        #pragma unroll
        for (int j = 0; j < 4; ++j) {
            float4 kk, vv;
            kk.x = Kr[4*j+0]; kk.y = Kr[4*j+1]; kk.z = Kr[4*j+2]; kk.w = Kr[4*j+3];
            vv.x = Vr[4*j+0]; vv.y = Vr[4*j+1]; vv.z = Vr[4*j+2]; vv.w = Vr[4*j+3];
            ((float4*)kdst)[j] = kk;
            ((float4*)vdst)[j] = vv;
        }
    }
    __syncthreads();

    // ---------------- attention (seq=8, per-thread softmax) ----------------
    float sc[SEQ];
    #pragma unroll
    for (int m = 0; m < SEQ; ++m) {
        const float* kr = sK + i * ITEM_STRIDE + m * DIM;
        float s = 0.f;
        #pragma unroll
        for (int d = 0; d < DIM; ++d) s += Q[d] * kr[d];
        sc[m] = s * 0.25f;  // 1/sqrt(16)
    }
    float mx = sc[0];
    #pragma unroll
    for (int m = 1; m < SEQ; ++m) mx = fmaxf(mx, sc[m]);
    float sum = 0.f;
    #pragma unroll
    for (int m = 0; m < SEQ; ++m) { sc[m] = __expf(sc[m] - mx); sum += sc[m]; }
    const float inv = 1.0f / sum;

    float at[DIM];
    #pragma unroll
    for (int d = 0; d < DIM; ++d) at[d] = 0.f;
    #pragma unroll
    for (int m = 0; m < SEQ; ++m) {
        const float w = sc[m] * inv;
        const float* vr = sV + i * ITEM_STRIDE + m * DIM;
        #pragma unroll
        for (int d = 0; d < DIM; ++d) at[d] += w * vr[d];
    }

    // ---------------- O projection + residual ----------------
    float X1[DIM];
    #pragma unroll
    for (int e = 0; e < DIM; ++e) {
        float o = bo[e];
        #pragma unroll
        for (int d = 0; d < DIM; ++d) o += at[d] * Wo[d * DIM + e];
        X1[e] = X[e] + o;
    }

    // ---------------- FFN + residual ----------------
    float h[FF];
    #pragma unroll
    for (int f = 0; f < FF; ++f) {
        float a = b1[f];
        #pragma unroll
        for (int d = 0; d < DIM; ++d) a += X1[d] * W1[d * FF + f];
        h[f] = fmaxf(a, 0.f);
    }
    float X2[DIM];
    #pragma unroll
    for (int e = 0; e < DIM; ++e) {
        float a = b2[e];
        #pragma unroll
        for (int f = 0; f < FF; ++f) a += h[f] * W2[f * DIM + e];
        X2[e] = X1[e] + a;
    }

    __syncthreads();  // everyone done reading sK/sV

    // park final X rows in LDS (reuse sK)
    {
        float* xdst = sK + i * ITEM_STRIDE + n * DIM;
        #pragma unroll
        for (int j = 0; j < 4; ++j) {
            float4 xx;
            xx.x = X2[4*j+0]; xx.y = X2[4*j+1]; xx.z = X2[4*j+2]; xx.w = X2[4*j+3];
            ((float4*)xdst)[j] = xx;
        }
    }
    __syncthreads();

    // ---------------- phase 2: vocab head, coalesced writes ----------------
    // thread t owns vocab column t; W_head is [DIM][VOCAB] row-major.
    float wh[DIM];
    #pragma unroll
    for (int d = 0; d < DIM; ++d) wh[d] = Wh[d * VOCAB + tid];
    const float bhv = bh[tid];

    const size_t obase = (size_t)blockIdx.x * (ITEMS_PER_BLOCK * SEQ) * VOCAB + tid;
    #pragma unroll 4
    for (int r = 0; r < ITEMS_PER_BLOCK * SEQ; ++r) {
        const float* xr = sK + (r >> 3) * ITEM_STRIDE + (r & 7) * DIM;
        float acc = bhv;
        #pragma unroll
        for (int d = 0; d < DIM; ++d) acc += xr[d] * wh[d];
        out[obase + (size_t)r * VOCAB] = acc;
    }
}

extern "C" void kernel_launch(void* const* d_in, const int* in_sizes, int n_in,
                              void* d_out, int out_size, void* d_ws, size_t ws_size,
                              hipStream_t stream) {
    const int*   x           = (const int*)  d_in[0];
    const float* token_embed = (const float*)d_in[1];
    const float* pos_embed   = (const float*)d_in[2];
    const float* Wq = (const float*)d_in[3];
    const float* bq = (const float*)d_in[4];
    const float* Wk = (const float*)d_in[5];
    const float* bk = (const float*)d_in[6];
    const float* Wv = (const float*)d_in[7];
    const float* bv = (const float*)d_in[8];
    const float* Wo = (const float*)d_in[9];
    const float* bo = (const float*)d_in[10];
    const float* W1 = (const float*)d_in[11];
    const float* b1 = (const float*)d_in[12];
    const float* W2 = (const float*)d_in[13];
    const float* b2 = (const float*)d_in[14];
    const float* Wh = (const float*)d_in[15];
    const float* bh = (const float*)d_in[16];
    float* out = (float*)d_out;

    const int B = in_sizes[0] / SEQ;                 // 32768
    const int grid = B / ITEMS_PER_BLOCK;            // 1024 blocks
    transformer_fused_kernel<<<grid, 256, 0, stream>>>(
        x, token_embed, pos_embed, Wq, bq, Wk, bk, Wv, bv, Wo, bo,
        W1, b1, W2, b2, Wh, bh, out);
}